// Round 5
// baseline (376.941 us; speedup 1.0000x reference)
//
#include <hip/hip_runtime.h>
#include <math.h>

// MelGaussianFilteredMSE:
//   diff = 10^(mo/10) - 10^(tg/10)            (B=32, F=1025, T=2000, fp32)
//   out  = mean( (M @ diff along F)^2 )       M is BANDED: half-width <= 10
//
// R4: vmcnt hygiene. Stream loads are the ONLY global loads in the main loop
// (prefetch ring depth 3, float2/thread); coefficients live in LDS and are
// read as 6x ds_read_b128 per output row (lgkmcnt — independent of vmcnt).
// R3's bug: per-row coeff loads were global -> in-order vmcnt drained the
// stream ring every output row, capping BW at ~1.5 TB/s.
// OOB input rows are handled by ZERO COEFFICIENTS (band staging zero-pads),
// so edge chunks just clamp the load address — no mask multiply.

#define B_N 32
#define F_N 1025
#define T_N 2000

#define NOUT   106   // output rows per f-chunk
#define ROWS   126   // NOUT + 20 halo = 6*21
#define NCHUNK 10
#define NT     256   // threads per block
#define CT     512   // t-columns per block (256 threads * 2)
#define PF     3     // prefetch ring depth (3 | 21 -> static ring slots)
#define CST    24    // coeff LDS row stride in floats (96 B, 16B-aligned)

#define LOG2_10_DIV10 0.33219280948873623f   // 10^(x/10) = 2^(x*this)

__global__ __launch_bounds__(NT, 5)
void mel_mse_stream(const float* __restrict__ mo_g, const float* __restrict__ tg_g,
                    const float* __restrict__ M, float* __restrict__ partials) {
    __shared__ float sm[NOUT * CST];   // 106*24*4 = 10176 B
    __shared__ float red[NT];

    const int tid  = threadIdx.x;
    const int t0   = blockIdx.x * CT;
    const int f0   = blockIdx.y * NOUT;
    const int b    = blockIdx.z;
    const int base = f0 - 10;                 // global input row of stream step 0
    const int t    = t0 + tid * 2;
    const bool colv = (t + 1 < T_N);          // T_N even: pair fully valid or not
    const int tc    = colv ? t : 0;

    // ---- stage the 21-wide coefficient band, zero-padded to CST ----
    for (int i = tid; i < NOUT * CST; i += NT) {
        const int row = i / CST;
        const int j   = i - row * CST;
        const int f   = f0 + row;
        const int k   = f - 10 + j;
        float v = 0.f;
        if (j < 21 && f < F_N && k >= 0 && k < F_N) v = M[(size_t)f * F_N + k];
        sm[i] = v;
    }
    __syncthreads();

    float2 w[21];                             // diff window (static-indexed)
    float2 ra[PF], rc[PF];                    // raw prefetch rings
    float2 acc = make_float2(0.f, 0.f);

    // emit output row r_out (chunk-local); s0 = window slot of tap 0 (static)
    auto OUT = [&](int r_out, int s0) {
        float cf[24];
        const float4* c4 = reinterpret_cast<const float4*>(&sm[r_out * CST]);
#pragma unroll
        for (int q = 0; q < 6; ++q)
            *reinterpret_cast<float4*>(&cf[q * 4]) = c4[q];   // ds_read_b128 x6
        float2 o = make_float2(0.f, 0.f);
#pragma unroll
        for (int j = 0; j < 21; ++j) {
            const float2 wv = w[(s0 + j) % 21];
            o.x = fmaf(cf[j], wv.x, o.x);
            o.y = fmaf(cf[j], wv.y, o.y);
        }
        acc.x = fmaf(o.x, o.x, acc.x);
        acc.y = fmaf(o.y, o.y, acc.y);
    };
    // consume ring slot s -> diff -> window slot ws
    auto CONS = [&](int s, int ws) {
        const float2 a = ra[s], c = rc[s];
        w[ws].x = exp2f(a.x * LOG2_10_DIV10) - exp2f(c.x * LOG2_10_DIV10);
        w[ws].y = exp2f(a.y * LOG2_10_DIV10) - exp2f(c.y * LOG2_10_DIV10);
    };

    const bool fast = (base >= 0) && (base + ROWS <= F_N);    // uniform per block

    if (fast) {
        const float* pm = mo_g + ((size_t)b * F_N + base) * (size_t)T_N + tc;
        const float* pt = tg_g + ((size_t)b * F_N + base) * (size_t)T_N + tc;
        auto ISSUE = [&](int s) {                             // sequential rows
            ra[s] = *reinterpret_cast<const float2*>(pm);
            rc[s] = *reinterpret_cast<const float2*>(pt);
            pm += T_N; pt += T_N;
        };
#pragma unroll
        for (int i = 0; i < PF; ++i) ISSUE(i);                // rows 0..2
#pragma unroll
        for (int i = 0; i < 21; ++i) {                        // rows 0..20
            CONS(i % PF, i);
            ISSUE(i % PF);                                    // rows 3..23
            if (i == 20) OUT(0, 0);
        }
        for (int m = 1; m < 5; ++m) {                         // rows 21..104
#pragma unroll
            for (int i = 0; i < 21; ++i) {
                CONS(i % PF, i);
                ISSUE(i % PF);                                // rows nb+3..nb+23
                OUT(m * 21 + i - 20, (i + 1) % 21);
            }
        }
#pragma unroll
        for (int i = 0; i < 21; ++i) {                        // rows 105..125
            CONS(i % PF, i);
            if (i < ROWS - 105 - PF) ISSUE(i % PF);           // rows 108..125
            OUT(105 + i - 20, (i + 1) % 21);
        }
    } else {
        const size_t colbase = ((size_t)b * F_N) * (size_t)T_N + tc;
        auto ISSUE = [&](int n, int s) {                      // clamped row n
            int g = base + n;
            g = g < 0 ? 0 : (g > F_N - 1 ? F_N - 1 : g);      // OOB -> coeff is 0
            const size_t off = colbase + (size_t)g * T_N;
            ra[s] = *reinterpret_cast<const float2*>(mo_g + off);
            rc[s] = *reinterpret_cast<const float2*>(tg_g + off);
        };
#pragma unroll
        for (int i = 0; i < PF; ++i) ISSUE(i, i);
#pragma unroll
        for (int i = 0; i < 21; ++i) {
            CONS(i % PF, i);
            ISSUE(i + PF, i % PF);
            if (i == 20) OUT(0, 0);
        }
        for (int m = 1; m < 5; ++m) {
            const int nb = m * 21;
#pragma unroll
            for (int i = 0; i < 21; ++i) {
                CONS(i % PF, i);
                ISSUE(nb + i + PF, i % PF);
                OUT(nb + i - 20, (i + 1) % 21);
            }
        }
#pragma unroll
        for (int i = 0; i < 21; ++i) {
            CONS(i % PF, i);
            if (i < ROWS - 105 - PF) ISSUE(105 + i + PF, i % PF);
            OUT(105 + i - 20, (i + 1) % 21);
        }
    }

    // ---- block reduction ----
    red[tid] = colv ? (acc.x + acc.y) : 0.f;
    __syncthreads();
    for (int s = NT / 2; s > 0; s >>= 1) {
        if (tid < s) red[tid] += red[tid + s];
        __syncthreads();
    }
    if (tid == 0) {
        const int bid = blockIdx.x + gridDim.x * (blockIdx.y + gridDim.y * blockIdx.z);
        partials[bid] = red[0];
    }
}

__global__ void mel_mse_reduce(const float* __restrict__ partials, int n,
                               float* __restrict__ out) {
    __shared__ double red[256];
    double s = 0.0;
    for (int i = threadIdx.x; i < n; i += 256) s += (double)partials[i];
    red[threadIdx.x] = s;
    __syncthreads();
    for (int st = 128; st > 0; st >>= 1) {
        if (threadIdx.x < st) red[threadIdx.x] += red[threadIdx.x + st];
        __syncthreads();
    }
    if (threadIdx.x == 0)
        out[0] = (float)(red[0] / (double)((long long)B_N * F_N * T_N));
}

extern "C" void kernel_launch(void* const* d_in, const int* in_sizes, int n_in,
                              void* d_out, int out_size, void* d_ws, size_t ws_size,
                              hipStream_t stream) {
    const float* mo = (const float*)d_in[0];   // model_output (32,1025,2000) fp32
    const float* tg = (const float*)d_in[1];   // target       (32,1025,2000) fp32
    const float* M  = (const float*)d_in[2];   // transform_matrix (1025,1025) fp32
    float* out      = (float*)d_out;
    float* partials = (float*)d_ws;            // 4*10*32*4 = 5120 B

    dim3 grid((T_N + CT - 1) / CT,             // 4 t-tiles
              NCHUNK,                          // 10 f-chunks
              B_N);                            // 32 batches -> 1280 blocks = 5/CU
    const int nparts = grid.x * grid.y * grid.z;

    mel_mse_stream<<<grid, NT, 0, stream>>>(mo, tg, M, partials);
    mel_mse_reduce<<<1, 256, 0, stream>>>(partials, nparts, out);
}

// Round 6
// 203.233 us; speedup vs baseline: 1.8547x; 1.8547x over previous
//
#include <hip/hip_runtime.h>
#include <math.h>

// MelGaussianFilteredMSE:
//   diff = 10^(mo/10) - 10^(tg/10)            (B=32, F=1025, T=2000, fp32)
//   out  = mean( (M @ diff along F)^2 )       M is BANDED: half-width <= 10
//
// R5: every prior structure plateaued at ~1.6 TB/s HBM. Suspects: narrow
// lane loads (4-8B) and icache thrash from full unrolling (~50 KB code).
// This round: float4 (16B) lane loads; 1-wave blocks (no barriers, shuffle
// reduction); rolled macro-loop (one 21-row body, executed 9x + peel) so the
// hot loop fits I$; all row addressing scalar (uniform clamp, ONE code path);
// coefficients read as provably-uniform loads (-> s_load/SGPRs) from a
// pre-packed zero-padded band; prefetch ring depth 2.

#define B_N 32
#define F_N 1025
#define T_N 2000

#define NOUT    190                  // output rows per f-chunk
#define RSTREAM 210                  // NOUT + 20 halo = 10*21
#define NMB     10                   // macro-blocks of 21 rows
#define NCHUNK  6                    // 6*190 = 1140 >= 1025
#define CBS     24                   // band row stride (96 B, 16B-aligned)
#define BANDROWS (NCHUNK * NOUT)     // 1140 rows; rows >= 1025 are all-zero

#define K_E 0.33219280948873623f     // log2(10)/10 : 10^(x/10) = 2^(x*K_E)

__global__ void build_band(const float* __restrict__ M, float* __restrict__ band) {
    const int idx = blockIdx.x * 256 + threadIdx.x;
    if (idx >= BANDROWS * CBS) return;
    const int f = idx / CBS;
    const int j = idx - f * CBS;
    const int k = f - 10 + j;
    float v = 0.f;
    if (j < 21 && f < F_N && k >= 0 && k < F_N) v = M[(size_t)f * F_N + k];
    band[idx] = v;
}

__global__ __launch_bounds__(64, 4)
void mel_mse_stream(const float* __restrict__ mo_g, const float* __restrict__ tg_g,
                    const float* __restrict__ band, float* __restrict__ partials) {
    const int lane = threadIdx.x;
    const int t    = blockIdx.x * 256 + lane * 4;
    const int f0   = blockIdx.y * NOUT;        // uniform
    const int b    = blockIdx.z;               // uniform
    const bool colv = (t + 3 < T_N);
    const int  tc   = colv ? t : 0;            // per-lane column (floats)

    float4 w[21];                              // diff window (static-indexed)
    float4 ra[2], rc[2];                       // prefetch ring, depth 2
    float4 acc = make_float4(0.f, 0.f, 0.f, 0.f);

    // issue row n (stream index) into ring slot s; all row math is scalar
    auto ISSUE = [&](int n, int s) {
        int g = f0 - 10 + n;                                   // uniform
        g = g < 0 ? 0 : (g > F_N - 1 ? F_N - 1 : g);           // scalar clamp
        const float* mrow = mo_g + (size_t)(b * F_N + g) * T_N; // uniform base
        const float* trow = tg_g + (size_t)(b * F_N + g) * T_N;
        ra[s] = *reinterpret_cast<const float4*>(mrow + tc);
        rc[s] = *reinterpret_cast<const float4*>(trow + tc);
    };
    auto CONS = [&](int s, int ws) {
        const float4 a = ra[s], c = rc[s];
        w[ws].x = exp2f(a.x * K_E) - exp2f(c.x * K_E);
        w[ws].y = exp2f(a.y * K_E) - exp2f(c.y * K_E);
        w[ws].z = exp2f(a.z * K_E) - exp2f(c.z * K_E);
        w[ws].w = exp2f(a.w * K_E) - exp2f(c.w * K_E);
    };
    // emit global output row frow; s0 = window slot of tap 0 (compile-time)
    auto OUT = [&](int frow, int s0) {
        float cf[24];                                          // uniform -> SGPRs
        const float4* c4 = reinterpret_cast<const float4*>(band + (size_t)frow * CBS);
#pragma unroll
        for (int q = 0; q < 6; ++q)
            *reinterpret_cast<float4*>(&cf[4 * q]) = c4[q];
        float4 o = make_float4(0.f, 0.f, 0.f, 0.f);
#pragma unroll
        for (int j = 0; j < 21; ++j) {
            const float4 wv = w[(s0 + j) % 21];
            o.x = fmaf(cf[j], wv.x, o.x);
            o.y = fmaf(cf[j], wv.y, o.y);
            o.z = fmaf(cf[j], wv.z, o.z);
            o.w = fmaf(cf[j], wv.w, o.w);
        }
        acc.x = fmaf(o.x, o.x, acc.x);
        acc.y = fmaf(o.y, o.y, acc.y);
        acc.z = fmaf(o.z, o.z, acc.z);
        acc.w = fmaf(o.w, o.w, acc.w);
    };

    // prologue: rows 0,1 in flight
    ISSUE(0, 0);
    ISSUE(1, 1);

    // peeled macro-block 0: consume rows 0..20, first output at i == 20
#pragma unroll
    for (int i = 0; i < 21; ++i) {
        CONS(i & 1, i);
        ISSUE(i + 2, i & 1);                    // rows 2..22
        if (i == 20) OUT(f0, 0);
    }
    // steady state: macro-blocks 1..9 (rows 21..209), one output per row.
    // Rows 210,211 get issued (clamped, valid addresses) but never consumed.
    for (int mb = 1; mb < NMB; ++mb) {
        const int nb = mb * 21;
#pragma unroll
        for (int i = 0; i < 21; ++i) {
            CONS(i & 1, i);
            ISSUE(nb + i + 2, i & 1);
            OUT(f0 + nb + i - 20, (i + 1) % 21);
        }
    }

    // wave reduction (single wave per block, no LDS, no barrier)
    float local = colv ? (acc.x + acc.y + acc.z + acc.w) : 0.f;
#pragma unroll
    for (int off = 32; off > 0; off >>= 1)
        local += __shfl_xor(local, off, 64);
    if (lane == 0) {
        const int bid = blockIdx.x + gridDim.x * (blockIdx.y + gridDim.y * blockIdx.z);
        partials[bid] = local;
    }
}

__global__ void mel_mse_reduce(const float* __restrict__ partials, int n,
                               float* __restrict__ out) {
    __shared__ double red[256];
    double s = 0.0;
    for (int i = threadIdx.x; i < n; i += 256) s += (double)partials[i];
    red[threadIdx.x] = s;
    __syncthreads();
    for (int st = 128; st > 0; st >>= 1) {
        if (threadIdx.x < st) red[threadIdx.x] += red[threadIdx.x + st];
        __syncthreads();
    }
    if (threadIdx.x == 0)
        out[0] = (float)(red[0] / (double)((long long)B_N * F_N * T_N));
}

extern "C" void kernel_launch(void* const* d_in, const int* in_sizes, int n_in,
                              void* d_out, int out_size, void* d_ws, size_t ws_size,
                              hipStream_t stream) {
    const float* mo = (const float*)d_in[0];   // model_output (32,1025,2000) fp32
    const float* tg = (const float*)d_in[1];   // target       (32,1025,2000) fp32
    const float* M  = (const float*)d_in[2];   // transform_matrix (1025,1025) fp32
    float* out      = (float*)d_out;

    float* band     = (float*)d_ws;                        // 1140*24*4 = 109440 B
    float* partials = (float*)((char*)d_ws + 109568);      // 1536*4    =   6144 B

    build_band<<<(BANDROWS * CBS + 255) / 256, 256, 0, stream>>>(M, band);

    dim3 grid((T_N + 255) / 256,               // 8 t-tiles (256 cols/wave)
              NCHUNK,                          // 6 f-chunks
              B_N);                            // 32 batches -> 1536 one-wave blocks
    const int nparts = grid.x * grid.y * grid.z;   // 1536

    mel_mse_stream<<<grid, 64, 0, stream>>>(mo, tg, band, partials);
    mel_mse_reduce<<<1, 256, 0, stream>>>(partials, nparts, out);
}